// Round 6
// baseline (296.002 us; speedup 1.0000x reference)
//
#include <hip/hip_runtime.h>

#define DEVI __device__ __forceinline__

typedef __attribute__((ext_vector_type(8))) short short8;
typedef __attribute__((ext_vector_type(4))) short short4v;
typedef __attribute__((ext_vector_type(4))) float f32x4;
typedef __attribute__((ext_vector_type(4))) unsigned int u32x4;

#define ATTN_SCALE 0.10206207261596575f  // 96^-0.5
#define LOG2E      1.4426950408889634f
#define KSCALE     (ATTN_SCALE * LOG2E)

DEVI unsigned short f2bf(float f){
  unsigned u = __float_as_uint(f);
  u += 0x7fff + ((u >> 16) & 1);          // RNE
  return (unsigned short)(u >> 16);
}
DEVI float bf2f(unsigned short h){ return __uint_as_float(((unsigned)h) << 16); }

DEVI void gload16(const void* g, void* l){
  __builtin_amdgcn_global_load_lds((const __attribute__((address_space(1))) void*)g,
                                   (__attribute__((address_space(3))) void*)l, 16, 0, 0);
}

DEVI f32x4 mfma16(short8 a, short8 b, f32x4 c){
  return __builtin_amdgcn_mfma_f32_16x16x32_bf16(a, b, c, 0, 0, 0);
}

DEVI short8 pack_bf8s(const float* p, float s){   // 8 f32 * s -> bf16 x8
  float4 a = *(const float4*)p, b = *(const float4*)(p + 4);
  short8 r;
  r[0] = f2bf(a.x * s); r[1] = f2bf(a.y * s); r[2] = f2bf(a.z * s); r[3] = f2bf(a.w * s);
  r[4] = f2bf(b.x * s); r[5] = f2bf(b.y * s); r[6] = f2bf(b.z * s); r[7] = f2bf(b.w * s);
  return r;
}

// ---------------- K1: f32 -> bf16 convert (hidden), convert+transpose (qkv_w) ---
__global__ __launch_bounds__(256) void k_convert(const float4* __restrict__ hs4,
    const float* __restrict__ w, unsigned short* __restrict__ hsb,
    unsigned short* __restrict__ wt){
  const int stride = gridDim.x * 256;
  const int t0 = blockIdx.x * 256 + threadIdx.x;
  const int n4 = (50176 * 192) / 4;
  for (int i = t0; i < n4; i += stride){
    float4 v = hs4[i];
    uint2 p;
    p.x = (unsigned)f2bf(v.x) | ((unsigned)f2bf(v.y) << 16);
    p.y = (unsigned)f2bf(v.z) | ((unsigned)f2bf(v.w) << 16);
    ((uint2*)hsb)[i] = p;
  }
  for (int i = t0; i < 192 * 1152; i += stride){
    int k = i / 1152, n = i - k * 1152;
    wt[n * 192 + k] = f2bf(w[i]);
  }
}

// ---------------- K2: QKV GEMM  C[50176,1152] = A[50176,192] * W[192,1152] + b --
__global__ __launch_bounds__(256) void k_gemm(const unsigned short* __restrict__ A,
    const unsigned short* __restrict__ Bt,   // [1152][192] (pre-transposed, K-major)
    const float* __restrict__ bias, unsigned short* __restrict__ C){
  __shared__ unsigned short sA[2][128 * 64];
  __shared__ unsigned short sB[2][128 * 64];
  // bijective XCD swizzle: 3528 = 8 * 441
  const int bid = (blockIdx.x & 7) * 441 + (blockIdx.x >> 3);
  const int bn = bid % 9, bm = bid / 9;
  const int tid = threadIdx.x, w = tid >> 6, l = tid & 63;
  const int wr = (w >> 1) * 64, wc = (w & 1) * 64;
  const int l15 = l & 15, l4 = l >> 4;
  const f32x4 z4 = {0.f, 0.f, 0.f, 0.f};
  f32x4 acc[4][4];
#pragma unroll
  for (int i = 0; i < 4; ++i)
#pragma unroll
    for (int j = 0; j < 4; ++j) acc[i][j] = z4;

  auto stage = [&](int kk, int buf){
    const int k0 = kk * 64;
#pragma unroll
    for (int i = 0; i < 4; ++i){
      const int ib = (w * 4 + i) << 10;
      const int Lb = ib + (l << 4);
      const int r  = Lb >> 7;
      const int g  = ((Lb >> 4) & 7) ^ (r & 7);
      gload16((const char*)A  + (size_t)(bm * 128 + r) * 384 + k0 * 2 + g * 16, (char*)sA[buf] + ib);
      gload16((const char*)Bt + (size_t)(bn * 128 + r) * 384 + k0 * 2 + g * 16, (char*)sB[buf] + ib);
    }
  };

  stage(0, 0);
  __syncthreads();
  for (int kk = 0; kk < 3; ++kk){
    const int buf = kk & 1;
    if (kk < 2) stage(kk + 1, buf ^ 1);
#pragma unroll
    for (int ks = 0; ks < 2; ++ks){
      short8 av[4], bv[4];
#pragma unroll
      for (int mf = 0; mf < 4; ++mf){
        const int r = wr + mf * 16 + l15;
        const int slot = (ks * 4 + l4) ^ (r & 7);
        av[mf] = *(const short8*)(sA[buf] + r * 64 + slot * 8);
      }
#pragma unroll
      for (int nf = 0; nf < 4; ++nf){
        const int r = wc + nf * 16 + l15;
        const int slot = (ks * 4 + l4) ^ (r & 7);
        bv[nf] = *(const short8*)(sB[buf] + r * 64 + slot * 8);
      }
#pragma unroll
      for (int mf = 0; mf < 4; ++mf)
#pragma unroll
        for (int nf = 0; nf < 4; ++nf)
          acc[mf][nf] = mfma16(av[mf], bv[nf], acc[mf][nf]);
    }
    if (kk < 2) __syncthreads();
  }
#pragma unroll
  for (int nf = 0; nf < 4; ++nf){
    const int col = bn * 128 + wc + nf * 16 + l15;
    const float bv = bias[col];
#pragma unroll
    for (int mf = 0; mf < 4; ++mf)
#pragma unroll
      for (int reg = 0; reg < 4; ++reg){
        const int row = bm * 128 + wr + mf * 16 + l4 * 4 + reg;
        C[(size_t)row * 1152 + col] = f2bf(acc[mf][nf][reg] + bv);
      }
  }
}

// ---------------- K3: depthwise 3x3 s2 pool + LayerNorm (vectorized) -----------
// kp is the EXTENDED K' [bh][784][160]: cols 0-95 = K*KSCALE (bf16),
// 96-123 = onehot(kh=n/28), 124-127 = 0, 128-155 = onehot(kw=n%28), 156-159 = 0.
__global__ __launch_bounds__(384) void k_pool_ln(const unsigned short* __restrict__ qkv,
    const float* __restrict__ wq, const float* __restrict__ wk, const float* __restrict__ wv,
    const float* __restrict__ gq, const float* __restrict__ bq,
    const float* __restrict__ gk, const float* __restrict__ bk,
    const float* __restrict__ gv, const float* __restrict__ bv,
    unsigned short* __restrict__ qp, unsigned short* __restrict__ kp,
    unsigned short* __restrict__ vpt, float* __restrict__ qpf){
  __shared__ float swt[9 * 96];          // weights transposed [tap][d]
  __shared__ float sg[96], sb[96];
  __shared__ float sbuf[28 * 96];
  const int bid = blockIdx.x;
  const int oy = bid % 28, h = (bid / 28) & 3, b = (bid / 112) & 15, which = bid / 1792;
  const float* wsel = which == 0 ? wq : (which == 1 ? wk : wv);
  const float* gsel = which == 0 ? gq : (which == 1 ? gk : gv);
  const float* bsel = which == 0 ? bq : (which == 1 ? bk : bv);
  const int tid = threadIdx.x;
  for (int i = tid; i < 864; i += 384){
    const int d = i / 9, t = i - d * 9;
    swt[t * 96 + d] = wsel[i];
  }
  if (tid < 96){ sg[tid] = gsel[tid]; sb[tid] = bsel[tid]; }
  __syncthreads();

  const int colbase = which * 384 + h * 96;
  if (tid < 336){
    const int ox = tid / 12, d0 = (tid - ox * 12) * 8;
    float acc[8] = {0.f,0.f,0.f,0.f,0.f,0.f,0.f,0.f};
#pragma unroll
    for (int ky = 0; ky < 3; ++ky){
      const int iy = oy * 2 + ky - 1;
      if ((unsigned)iy >= 56u) continue;
      const unsigned short* rowp = qkv + (size_t)(b * 3136 + iy * 56) * 1152 + colbase + d0;
#pragma unroll
      for (int kx = 0; kx < 3; ++kx){
        const int ix = ox * 2 + kx - 1;
        if ((unsigned)ix >= 56u) continue;
        const u32x4 raw = *(const u32x4*)(rowp + (size_t)ix * 1152);
        const float* wv8 = swt + (ky * 3 + kx) * 96 + d0;
        const float4 wa = *(const float4*)wv8;
        const float4 wb = *(const float4*)(wv8 + 4);
        acc[0] += __uint_as_float(raw[0] << 16)         * wa.x;
        acc[1] += __uint_as_float(raw[0] & 0xffff0000u) * wa.y;
        acc[2] += __uint_as_float(raw[1] << 16)         * wa.z;
        acc[3] += __uint_as_float(raw[1] & 0xffff0000u) * wa.w;
        acc[4] += __uint_as_float(raw[2] << 16)         * wb.x;
        acc[5] += __uint_as_float(raw[2] & 0xffff0000u) * wb.y;
        acc[6] += __uint_as_float(raw[3] << 16)         * wb.z;
        acc[7] += __uint_as_float(raw[3] & 0xffff0000u) * wb.w;
      }
    }
    *(float4*)(sbuf + ox * 96 + d0)     = *(float4*)acc;
    *(float4*)(sbuf + ox * 96 + d0 + 4) = *(float4*)(acc + 4);
  }
  __syncthreads();

  // LN: 8 lanes per row, 12 channels per lane, 28 rows in one pass
  const int grp = tid >> 3, l8 = tid & 7;
  if (grp < 28){
    const int ox = grp, d0 = l8 * 12;
    float x[12];
    *(float4*)x       = *(const float4*)(sbuf + ox * 96 + d0);
    *(float4*)(x + 4) = *(const float4*)(sbuf + ox * 96 + d0 + 4);
    *(float4*)(x + 8) = *(const float4*)(sbuf + ox * 96 + d0 + 8);
    float s = 0.f, ss = 0.f;
#pragma unroll
    for (int j = 0; j < 12; ++j){ s += x[j]; ss += x[j] * x[j]; }
#pragma unroll
    for (int d = 1; d < 8; d <<= 1){ s += __shfl_xor(s, d); ss += __shfl_xor(ss, d); }
    const float mean = s * (1.f / 96.f);
    const float var  = ss * (1.f / 96.f) - mean * mean;
    const float rstd = rsqrtf(var + 1e-6f);
    const int n = oy * 28 + ox;
    const size_t bh = (size_t)(b * 4 + h);
    float y[12];
#pragma unroll
    for (int j = 0; j < 12; ++j)
      y[j] = (x[j] - mean) * rstd * sg[d0 + j] + sb[d0 + j];
    if (which == 0){
      const size_t idx = (bh * 784 + n) * 96 + d0;
#pragma unroll
      for (int c = 0; c < 3; ++c){
        short4v p;
        p[0] = (short)f2bf(y[c*4]);   p[1] = (short)f2bf(y[c*4+1]);
        p[2] = (short)f2bf(y[c*4+2]); p[3] = (short)f2bf(y[c*4+3]);
        *(short4v*)(qp + idx + c * 4) = p;
        *(float4*)(qpf + idx + c * 4) = *(const float4*)(y + c * 4);
      }
    } else if (which == 1){
      const size_t idx = (bh * 784 + n) * 160;
#pragma unroll
      for (int c = 0; c < 3; ++c){
        short4v p;
        p[0] = (short)f2bf(y[c*4]   * KSCALE); p[1] = (short)f2bf(y[c*4+1] * KSCALE);
        p[2] = (short)f2bf(y[c*4+2] * KSCALE); p[3] = (short)f2bf(y[c*4+3] * KSCALE);
        *(short4v*)(kp + idx + d0 + c * 4) = p;
      }
      // one-hot extension granule (8 shorts at col 96 + l8*8)
      short8 oh;
#pragma unroll
      for (int jj = 0; jj < 8; ++jj){
        const int pcol = 96 + l8 * 8 + jj;
        unsigned short v = 0;
        if (pcol == 96 + oy)  v = 0x3F80;   // 1.0 bf16
        if (pcol == 128 + ox) v = 0x3F80;
        oh[jj] = (short)v;
      }
      *(short8*)(kp + idx + 96 + l8 * 8) = oh;
    } else {
#pragma unroll
      for (int j = 0; j < 12; ++j)
        vpt[(bh * 96 + d0 + j) * 784 + n] = f2bf(y[j]);
    }
  }
}

// ---------------- K4: fused attention, kv-split flash (partials out) ----------
// 896 blocks: (bh, qb, kvh). Each: 128 q-rows x keys[kvh-half]. Writes
// unnormalized O + (m,l) partials. K' LDS split: sKm 256B rows (XOR r&7,
// conflict-free) + sKe 64B rows (XOR (r>>1)&3, conflict-free). LDS 52KB.
__global__ __launch_bounds__(512, 4) void k_attn(
    const unsigned short* __restrict__ qp, const unsigned short* __restrict__ kp,
    const unsigned short* __restrict__ vpt,
    const float* __restrict__ relh, const float* __restrict__ relw,
    float* __restrict__ po, float2* __restrict__ pml){
  __shared__ unsigned short sKm[2][64 * 128];  // 2 x 16KB main (K cols 0..127)
  __shared__ unsigned short sKe[2][64 * 32];   // 2 x 4KB  ext  (K cols 128..159)
  __shared__ unsigned short sV[96 * 64];       // 12KB V^T tile [d][k]

  // XCD mapping: all 14 sub-blocks of one bh land on one XCD
  const int s = blockIdx.x, xcd = s & 7, slot = s >> 3;
  const int bh = xcd * 8 + slot / 14;
  const int rem = slot - (slot / 14) * 14;
  const int qb = rem >> 1, kvh = rem & 1;
  const int tid = threadIdx.x, w = tid >> 6, l = tid & 63;
  const int l15 = l & 15, l4 = l >> 4;
  const size_t baseq = (size_t)bh * 784 * 96;
  const size_t basek = (size_t)bh * 784 * 160;
  const f32x4 z4 = {0.f, 0.f, 0.f, 0.f};
  const int qrl = w * 16 + l15;                 // local q row 0..127
  int q_l = qb * 128 + qrl; if (q_l > 783) q_l = 783;
  const int t0 = kvh ? 7 : 0, t1 = kvh ? 13 : 7;

  auto stageK = [&](int t, int buf){
    int krr = t * 64;
#pragma unroll
    for (int rd = 0; rd < 2; ++rd){
      const int off = rd * 8192 + (tid << 4);
      const int row = off >> 8;                  // 256B rows
      const int gr  = (off >> 4) & 15;
      const int sg_ = (gr & 8) | ((gr ^ row) & 7);
      int kr = krr + row; if (kr > 783) kr = 783;
      gload16((const char*)kp + ((size_t)kr * 160 + basek + sg_ * 8) * 2,
              (char*)sKm[buf] + off);
    }
    if (tid < 256){
      const int off = tid << 4;
      const int row = off >> 6;                  // 64B rows
      const int gr  = (off >> 4) & 3;
      const int sg_ = (gr ^ (row >> 1)) & 3;
      int kr = krr + row; if (kr > 783) kr = 783;
      gload16((const char*)kp + ((size_t)kr * 160 + basek + 128 + sg_ * 8) * 2,
              (char*)sKe[buf] + off);
    }
  };
  short8 vreg[2];
  auto loadV = [&](int t){
    if (tid < 384){
#pragma unroll
      for (int i = 0; i < 2; ++i){
        const int off = (tid * 2 + i) << 4;      // bytes in sV
        const int r = off >> 7;                  // d row (128B rows)
        const int g = ((off >> 4) & 7) ^ (r & 7);
        int koff = t * 64 + g * 8; if (koff + 8 > 784) koff = 0;  // masked by P=0
        vreg[i] = *(const short8*)(vpt + (size_t)(bh * 96 + r) * 784 + koff);
      }
    }
  };
  auto writeV = [&](){
    if (tid < 384){
#pragma unroll
      for (int i = 0; i < 2; ++i)
        *(short8*)((char*)sV + ((tid * 2 + i) << 4)) = vreg[i];
    }
  };

  stageK(t0, 0);
  loadV(t0);

  // ---- Q' fragments: qf[0..2] = Q (bf16), qf[3] = Gh, qf[4] = Gw ----
  short8 qf[5];
#pragma unroll
  for (int ks = 0; ks < 3; ++ks)
    qf[ks] = *(const short8*)(qp + baseq + (size_t)q_l * 96 + ks * 32 + l4 * 8);

  const int hh = (q_l * 2341) >> 16;             // /28 (exact for <=847)
  const int ww = q_l - hh * 28;
  const int h0 = (qb * 128) / 28;

  // G tables via MFMA (log2e folded): overlay on sKm[1] (freed before prefetch)
  {
    unsigned short* sGh = sKm[1];
    unsigned short* sGw = sKm[1] + 4096;
    f32x4 gh[3] = {z4, z4, z4}, gw[4] = {z4, z4, z4, z4};
#pragma unroll
    for (int nf = 0; nf < 3; ++nf){
      int j = h0 + nf * 16 + l15; if (j > 54) j = 54;
#pragma unroll
      for (int ks = 0; ks < 3; ++ks)
        gh[nf] = mfma16(pack_bf8s(relh + j * 96 + ks * 32 + l4 * 8, LOG2E), qf[ks], gh[nf]);
    }
#pragma unroll
    for (int nf = 0; nf < 4; ++nf){
      int j = nf * 16 + l15; if (j > 54) j = 54;
#pragma unroll
      for (int ks = 0; ks < 3; ++ks)
        gw[nf] = mfma16(pack_bf8s(relw + j * 96 + ks * 32 + l4 * 8, LOG2E), qf[ks], gw[nf]);
    }
    if (l4 == 0){
      *(short4v*)(sGh + qrl * 32 + 28) = (short4v)0;
      *(short4v*)(sGw + qrl * 32 + 28) = (short4v)0;
    }
#pragma unroll
    for (int nf = 0; nf < 3; ++nf)
#pragma unroll
      for (int reg = 0; reg < 4; ++reg){
        const int j = h0 + nf * 16 + l4 * 4 + reg;
        const int kh = hh + 27 - j;
        if ((unsigned)kh < 28u) sGh[qrl * 32 + kh] = f2bf(gh[nf][reg]);
      }
#pragma unroll
    for (int nf = 0; nf < 4; ++nf)
#pragma unroll
      for (int reg = 0; reg < 4; ++reg){
        const int j = nf * 16 + l4 * 4 + reg;
        const int kw = ww + 27 - j;
        if ((unsigned)kw < 28u) sGw[qrl * 32 + kw] = f2bf(gw[nf][reg]);
      }
    qf[3] = *(const short8*)(sGh + qrl * 32 + l4 * 8);
    qf[4] = *(const short8*)(sGw + qrl * 32 + l4 * 8);
  }

  float m = -1e30f, lsum = 0.f;
  f32x4 acc[6];
#pragma unroll
  for (int i = 0; i < 6; ++i) acc[i] = z4;

  writeV();
  __syncthreads();   // drains K'(t0) staging; sV visible; sG reads done

  for (int t = t0; t < t1; ++t){
    const int cur = (t - t0) & 1;
    if (t + 1 < t1){ loadV(t + 1); stageK(t + 1, cur ^ 1); }

    // ---- S'^T = mfma(K', Q'): finished log2-logits, lane holds k-rows ----
    f32x4 sfr[4] = {z4, z4, z4, z4};
#pragma unroll
    for (int ks = 0; ks < 4; ++ks){
      const int g = ks * 4 + l4;
#pragma unroll
      for (int nf = 0; nf < 4; ++nf){
        const int r = nf * 16 + l15;
        const int sl = (g & 8) | ((g ^ r) & 7);
        const short8 kb = *(const short8*)(sKm[cur] + r * 128 + sl * 8);
        sfr[nf] = mfma16(kb, qf[ks], sfr[nf]);
      }
    }
#pragma unroll
    for (int nf = 0; nf < 4; ++nf){
      const int r = nf * 16 + l15;
      const int sl = (l4 ^ (r >> 1)) & 3;
      const short8 kb = *(const short8*)(sKe[cur] + r * 32 + sl * 8);
      sfr[nf] = mfma16(kb, qf[4], sfr[nf]);
    }
    if (t == 12){                 // keys 784..831 invalid: frags nf>=1
      const f32x4 m30 = {-1e30f, -1e30f, -1e30f, -1e30f};
      sfr[1] = m30; sfr[2] = m30; sfr[3] = m30;
    }

    // ---- lane-local online softmax (log2 domain) ----
    float mx;
    {
      float a0 = fmaxf(fmaxf(sfr[0][0], sfr[0][1]), fmaxf(sfr[0][2], sfr[0][3]));
      float a1 = fmaxf(fmaxf(sfr[1][0], sfr[1][1]), fmaxf(sfr[1][2], sfr[1][3]));
      float a2 = fmaxf(fmaxf(sfr[2][0], sfr[2][1]), fmaxf(sfr[2][2], sfr[2][3]));
      float a3 = fmaxf(fmaxf(sfr[3][0], sfr[3][1]), fmaxf(sfr[3][2], sfr[3][3]));
      mx = fmaxf(fmaxf(a0, a1), fmaxf(a2, a3));
    }
    mx = fmaxf(mx, __shfl_xor(mx, 16));
    mx = fmaxf(mx, __shfl_xor(mx, 32));
    const float mn = fmaxf(m, mx);
    const float al = exp2f(m - mn);
    m = mn;
    float sum;
    {
#pragma unroll
      for (int nf = 0; nf < 4; ++nf)
#pragma unroll
        for (int reg = 0; reg < 4; ++reg)
          sfr[nf][reg] = exp2f(sfr[nf][reg] - mn);
      float s0 = (sfr[0][0] + sfr[0][1]) + (sfr[0][2] + sfr[0][3]);
      float s1 = (sfr[1][0] + sfr[1][1]) + (sfr[1][2] + sfr[1][3]);
      float s2 = (sfr[2][0] + sfr[2][1]) + (sfr[2][2] + sfr[2][3]);
      float s3 = (sfr[3][0] + sfr[3][1]) + (sfr[3][2] + sfr[3][3]);
      sum = (s0 + s1) + (s2 + s3);
    }
    sum += __shfl_xor(sum, 16);
    sum += __shfl_xor(sum, 32);
    lsum = lsum * al + sum;

    __syncthreads();   // B1: all QK' reads of sKm/sKe[cur] done -> free for P

    // ---- P -> sKm[cur] (128 rows x 128B, per-wave-private rows) ----
    unsigned short* sPp = sKm[cur];
#pragma unroll
    for (int nf = 0; nf < 4; ++nf){
      short4v p4;
      p4[0] = (short)f2bf(sfr[nf][0]); p4[1] = (short)f2bf(sfr[nf][1]);
      p4[2] = (short)f2bf(sfr[nf][2]); p4[3] = (short)f2bf(sfr[nf][3]);
      char* dst = (char*)sPp + qrl * 128 + (((nf * 2 + (l4 >> 1)) ^ (l15 & 7)) << 4) + ((l4 & 1) << 3);
      *(short4v*)dst = p4;
    }
    // rescale O^T by per-lane alpha
#pragma unroll
    for (int i = 0; i < 6; ++i)
#pragma unroll
      for (int reg = 0; reg < 4; ++reg)
        acc[i][reg] *= al;

    // ---- O^T += mfma(V^T, P) ----
#pragma unroll
    for (int ks = 0; ks < 2; ++ks){
      const short8 pb = *(const short8*)((char*)sPp + qrl * 128 + (((ks * 4 + l4) ^ (l15 & 7)) << 4));
#pragma unroll
      for (int nf = 0; nf < 6; ++nf){
        const int r = nf * 16 + l15;
        const int sl = (ks * 4 + l4) ^ (r & 7);
        const short8 vb = *(const short8*)(sV + r * 64 + sl * 8);
        acc[nf] = mfma16(vb, pb, acc[nf]);
      }
    }

    if (t + 1 < t1){
      __syncthreads();   // B2: PV reads of sV + P done; staging drained
      writeV();
      __syncthreads();   // B3: sV(t+1) visible
    }
  }

  // ---- epilogue: write unnormalized partials ----
  const int qg = qb * 128 + qrl;
  if (qg < 784){
    const size_t row = (size_t)kvh * 64 * 784 + (size_t)bh * 784 + qg;
    float* pob = po + row * 96;
#pragma unroll
    for (int nf = 0; nf < 6; ++nf)
      *(f32x4*)(pob + nf * 16 + l4 * 4) = acc[nf];
    if (l4 == 0) pml[row] = make_float2(m, lsum);
  }
}

// ---------------- K5: combine kv-split halves + residual ----------------------
__global__ __launch_bounds__(256) void k_comb(const float* __restrict__ po,
    const float2* __restrict__ pml, const float* __restrict__ qpf,
    float* __restrict__ out){
  const int idx = blockIdx.x * 256 + threadIdx.x;   // over 64*784*24 float4s
  if (idx >= 64 * 784 * 24) return;
  const int d4 = idx % 24;
  const int t  = idx / 24;
  const int q  = t % 784;
  const int bh = t / 784;
  const int b = bh >> 2, h = bh & 3;
  const size_t row = (size_t)bh * 784 + q;
  const float2 ml1 = pml[row];
  const float2 ml2 = pml[(size_t)64 * 784 + row];
  const float M = fmaxf(ml1.x, ml2.x);
  const float w1 = exp2f(ml1.x - M), w2 = exp2f(ml2.x - M);
  const float rden = 1.f / (ml1.y * w1 + ml2.y * w2);
  const size_t obase = row * 96 + d4 * 4;
  const float4 o1 = *(const float4*)(po + obase);
  const float4 o2 = *(const float4*)(po + (size_t)64 * 784 * 96 + obase);
  const float4 qr = *(const float4*)(qpf + obase);
  float4 r;
  r.x = (o1.x * w1 + o2.x * w2) * rden + qr.x;
  r.y = (o1.y * w1 + o2.y * w2) * rden + qr.y;
  r.z = (o1.z * w1 + o2.z * w2) * rden + qr.z;
  r.w = (o1.w * w1 + o2.w * w2) * rden + qr.w;
  *(float4*)(out + ((size_t)b * 784 + q) * 384 + h * 96 + d4 * 4) = r;
}

// ---------------- launcher -----------------------------------------------------
extern "C" void kernel_launch(void* const* d_in, const int* in_sizes, int n_in,
                              void* d_out, int out_size, void* d_ws, size_t ws_size,
                              hipStream_t stream){
  const float* hs  = (const float*)d_in[0];
  const float* qw  = (const float*)d_in[1];
  const float* qb  = (const float*)d_in[2];
  const float* pwq = (const float*)d_in[3];
  const float* pwk = (const float*)d_in[4];
  const float* pwv = (const float*)d_in[5];
  const float* gq  = (const float*)d_in[6];
  const float* bq  = (const float*)d_in[7];
  const float* gk  = (const float*)d_in[8];
  const float* bk  = (const float*)d_in[9];
  const float* gv  = (const float*)d_in[10];
  const float* bv  = (const float*)d_in[11];
  const float* rh  = (const float*)d_in[12];
  const float* rw  = (const float*)d_in[13];
  float* out = (float*)d_out;

  char* ws = (char*)d_ws;
  size_t off = 0;
  auto take = [&](size_t n)->char*{ char* p = ws + off; off += (n + 255) & ~(size_t)255; return p; };
  unsigned short* hsb = (unsigned short*)take((size_t)50176 * 192 * 2);
  unsigned short* wtb = (unsigned short*)take((size_t)1152 * 192 * 2);
  unsigned short* qkv = (unsigned short*)take((size_t)50176 * 1152 * 2);
  unsigned short* qpb = (unsigned short*)take((size_t)64 * 784 * 96 * 2);
  unsigned short* kpb = (unsigned short*)take((size_t)64 * 784 * 160 * 2);   // extended K'
  unsigned short* vpt = (unsigned short*)take((size_t)64 * 784 * 96 * 2);
  float* qpf          = (float*)take((size_t)64 * 784 * 96 * 4);
  // partials overlay the dead qkv buffer (qkv unused after k_pool_ln):
  float*  po  = (float*)qkv;                         // 2*64*784*96 f32 = 38.5MB
  float2* pml = (float2*)(po + (size_t)2 * 64 * 784 * 96);  // 0.8MB

  hipLaunchKernelGGL(k_convert, dim3(1024), dim3(256), 0, stream,
                     (const float4*)hs, qw, hsb, wtb);
  hipLaunchKernelGGL(k_gemm, dim3(392 * 9), dim3(256), 0, stream, hsb, wtb, qb, qkv);
  hipLaunchKernelGGL(k_pool_ln, dim3(5376), dim3(384), 0, stream, qkv,
                     pwq, pwk, pwv, gq, bq, gk, bk, gv, bv, qpb, kpb, vpt, qpf);
  hipLaunchKernelGGL(k_attn, dim3(896), dim3(512), 0, stream,
                     qpb, kpb, vpt, rh, rw, po, pml);
  hipLaunchKernelGGL(k_comb, dim3((64 * 784 * 24 + 255) / 256), dim3(256), 0, stream,
                     po, pml, qpf, out);
}

// Round 8
// 259.572 us; speedup vs baseline: 1.1403x; 1.1403x over previous
//
#include <hip/hip_runtime.h>

#define DEVI __device__ __forceinline__

typedef __attribute__((ext_vector_type(8))) short short8;
typedef __attribute__((ext_vector_type(4))) short short4v;
typedef __attribute__((ext_vector_type(4))) float f32x4;
typedef __attribute__((ext_vector_type(4))) unsigned int u32x4;

#define ATTN_SCALE 0.10206207261596575f  // 96^-0.5
#define LOG2E      1.4426950408889634f
#define KSCALE     (ATTN_SCALE * LOG2E)

DEVI unsigned short f2bf(float f){
  unsigned u = __float_as_uint(f);
  u += 0x7fff + ((u >> 16) & 1);          // RNE
  return (unsigned short)(u >> 16);
}
DEVI float bf2f(unsigned short h){ return __uint_as_float(((unsigned)h) << 16); }

DEVI void gload16(const void* g, void* l){
  __builtin_amdgcn_global_load_lds((const __attribute__((address_space(1))) void*)g,
                                   (__attribute__((address_space(3))) void*)l, 16, 0, 0);
}

DEVI f32x4 mfma16(short8 a, short8 b, f32x4 c){
  return __builtin_amdgcn_mfma_f32_16x16x32_bf16(a, b, c, 0, 0, 0);
}

// ---------------- K1: f32->bf16 converts: hidden, qkv_w^T, rel tables ----------
__global__ __launch_bounds__(256) void k_convert(const float4* __restrict__ hs4,
    const float* __restrict__ w, const float* __restrict__ rh, const float* __restrict__ rw,
    unsigned short* __restrict__ hsb, unsigned short* __restrict__ wt,
    unsigned short* __restrict__ rhb, unsigned short* __restrict__ rwb){
  const int stride = gridDim.x * 256;
  const int t0 = blockIdx.x * 256 + threadIdx.x;
  const int n4 = (50176 * 192) / 4;
  for (int i = t0; i < n4; i += stride){
    float4 v = hs4[i];
    uint2 p;
    p.x = (unsigned)f2bf(v.x) | ((unsigned)f2bf(v.y) << 16);
    p.y = (unsigned)f2bf(v.z) | ((unsigned)f2bf(v.w) << 16);
    ((uint2*)hsb)[i] = p;
  }
  for (int i = t0; i < 192 * 1152; i += stride){
    int k = i / 1152, n = i - k * 1152;
    wt[n * 192 + k] = f2bf(w[i]);
  }
  for (int i = t0; i < 55 * 96; i += stride){
    rhb[i] = f2bf(rh[i] * LOG2E);
    rwb[i] = f2bf(rw[i] * LOG2E);
  }
}

// ---------------- K2: QKV GEMM  C[50176,1152] = A[50176,192] * W[192,1152] + b --
// Operand-swapped MFMA (lane holds 4 consecutive cols) + LDS-bounced coalesced
// C write (short8, 256B segments).
__global__ __launch_bounds__(256) void k_gemm(const unsigned short* __restrict__ A,
    const unsigned short* __restrict__ Bt,   // [1152][192] (pre-transposed, K-major)
    const float* __restrict__ bias, unsigned short* __restrict__ C){
  __shared__ unsigned short sA[2][128 * 64];
  __shared__ unsigned short sB[2][128 * 64];
  // bijective XCD swizzle: 3528 = 8 * 441
  const int bid = (blockIdx.x & 7) * 441 + (blockIdx.x >> 3);
  const int bn = bid % 9, bm = bid / 9;
  const int tid = threadIdx.x, w = tid >> 6, l = tid & 63;
  const int wr = (w >> 1) * 64, wc = (w & 1) * 64;
  const int l15 = l & 15, l4 = l >> 4;
  const f32x4 z4 = {0.f, 0.f, 0.f, 0.f};
  f32x4 acc[4][4];
#pragma unroll
  for (int i = 0; i < 4; ++i)
#pragma unroll
    for (int j = 0; j < 4; ++j) acc[i][j] = z4;

  auto stage = [&](int kk, int buf){
    const int k0 = kk * 64;
#pragma unroll
    for (int i = 0; i < 4; ++i){
      const int ib = (w * 4 + i) << 10;
      const int Lb = ib + (l << 4);
      const int r  = Lb >> 7;
      const int g  = ((Lb >> 4) & 7) ^ (r & 7);
      gload16((const char*)A  + (size_t)(bm * 128 + r) * 384 + k0 * 2 + g * 16, (char*)sA[buf] + ib);
      gload16((const char*)Bt + (size_t)(bn * 128 + r) * 384 + k0 * 2 + g * 16, (char*)sB[buf] + ib);
    }
  };

  stage(0, 0);
  __syncthreads();
  for (int kk = 0; kk < 3; ++kk){
    const int buf = kk & 1;
    if (kk < 2) stage(kk + 1, buf ^ 1);
#pragma unroll
    for (int ks = 0; ks < 2; ++ks){
      short8 av[4], bv[4];
#pragma unroll
      for (int mf = 0; mf < 4; ++mf){
        const int r = wr + mf * 16 + l15;
        const int slot = (ks * 4 + l4) ^ (r & 7);
        av[mf] = *(const short8*)(sA[buf] + r * 64 + slot * 8);
      }
#pragma unroll
      for (int nf = 0; nf < 4; ++nf){
        const int r = wc + nf * 16 + l15;
        const int slot = (ks * 4 + l4) ^ (r & 7);
        bv[nf] = *(const short8*)(sB[buf] + r * 64 + slot * 8);
      }
      // swapped operands: acc[mf][nf] holds C[row=wr+mf*16+l15][col=wc+nf*16+l4*4+reg]
#pragma unroll
      for (int mf = 0; mf < 4; ++mf)
#pragma unroll
        for (int nf = 0; nf < 4; ++nf)
          acc[mf][nf] = mfma16(bv[nf], av[mf], acc[mf][nf]);
    }
    if (kk < 2) __syncthreads();
  }

  // ---- epilogue: bias + bounce through LDS, coalesced short8 global stores ----
  __syncthreads();                            // all MFMA LDS reads done
  unsigned short* sC = (unsigned short*)sA;   // 32KB = 128 rows x 128 cols
#pragma unroll
  for (int nf = 0; nf < 4; ++nf){
    const int colq = wc + nf * 16 + l4 * 4;
    const float4 b4 = *(const float4*)(bias + bn * 128 + colq);
#pragma unroll
    for (int mf = 0; mf < 4; ++mf){
      const int row = wr + mf * 16 + l15;
      short4v p;
      p[0] = (short)f2bf(acc[mf][nf][0] + b4.x);
      p[1] = (short)f2bf(acc[mf][nf][1] + b4.y);
      p[2] = (short)f2bf(acc[mf][nf][2] + b4.z);
      p[3] = (short)f2bf(acc[mf][nf][3] + b4.w);
      const int slot = (colq >> 3) ^ (row & 7);
      *(short4v*)(sC + row * 128 + slot * 8 + (colq & 7)) = p;
    }
  }
  __syncthreads();
#pragma unroll
  for (int i = 0; i < 8; ++i){
    const int row = i * 16 + w * 4 + l4;
    const int slot = l15 ^ (row & 7);
    const short8 v = *(const short8*)(sC + row * 128 + slot * 8);
    *(short8*)(C + (size_t)(bm * 128 + row) * 1152 + bn * 128 + l15 * 8) = v;
  }
}

// ---------------- K3: depthwise 3x3 s2 pool + LayerNorm (vectorized) -----------
// kp is the EXTENDED K' [bh][784][160]: cols 0-95 = K*KSCALE (bf16),
// 96-123 = onehot(kh=n/28), 124-127 = 0, 128-155 = onehot(kw=n%28), 156-159 = 0.
__global__ __launch_bounds__(384) void k_pool_ln(const unsigned short* __restrict__ qkv,
    const float* __restrict__ wq, const float* __restrict__ wk, const float* __restrict__ wv,
    const float* __restrict__ gq, const float* __restrict__ bq,
    const float* __restrict__ gk, const float* __restrict__ bk,
    const float* __restrict__ gv, const float* __restrict__ bv,
    unsigned short* __restrict__ qp, unsigned short* __restrict__ kp,
    unsigned short* __restrict__ vpt, float* __restrict__ qpf){
  __shared__ float swt[9 * 96];          // weights transposed [tap][d]
  __shared__ float sg[96], sb[96];
  __shared__ float sbuf[28 * 96];
  const int bid = blockIdx.x;
  const int oy = bid % 28, h = (bid / 28) & 3, b = (bid / 112) & 15, which = bid / 1792;
  const float* wsel = which == 0 ? wq : (which == 1 ? wk : wv);
  const float* gsel = which == 0 ? gq : (which == 1 ? gk : gv);
  const float* bsel = which == 0 ? bq : (which == 1 ? bk : bv);
  const int tid = threadIdx.x;
  for (int i = tid; i < 864; i += 384){
    const int d = i / 9, t = i - d * 9;
    swt[t * 96 + d] = wsel[i];
  }
  if (tid < 96){ sg[tid] = gsel[tid]; sb[tid] = bsel[tid]; }
  __syncthreads();

  const int colbase = which * 384 + h * 96;
  if (tid < 336){
    const int ox = tid / 12, d0 = (tid - ox * 12) * 8;
    float acc[8] = {0.f,0.f,0.f,0.f,0.f,0.f,0.f,0.f};
#pragma unroll
    for (int ky = 0; ky < 3; ++ky){
      const int iy = oy * 2 + ky - 1;
      if ((unsigned)iy >= 56u) continue;
      const unsigned short* rowp = qkv + (size_t)(b * 3136 + iy * 56) * 1152 + colbase + d0;
#pragma unroll
      for (int kx = 0; kx < 3; ++kx){
        const int ix = ox * 2 + kx - 1;
        if ((unsigned)ix >= 56u) continue;
        const u32x4 raw = *(const u32x4*)(rowp + (size_t)ix * 1152);
        const float* wv8 = swt + (ky * 3 + kx) * 96 + d0;
        const float4 wa = *(const float4*)wv8;
        const float4 wb = *(const float4*)(wv8 + 4);
        acc[0] += __uint_as_float(raw[0] << 16)         * wa.x;
        acc[1] += __uint_as_float(raw[0] & 0xffff0000u) * wa.y;
        acc[2] += __uint_as_float(raw[1] << 16)         * wa.z;
        acc[3] += __uint_as_float(raw[1] & 0xffff0000u) * wa.w;
        acc[4] += __uint_as_float(raw[2] << 16)         * wb.x;
        acc[5] += __uint_as_float(raw[2] & 0xffff0000u) * wb.y;
        acc[6] += __uint_as_float(raw[3] << 16)         * wb.z;
        acc[7] += __uint_as_float(raw[3] & 0xffff0000u) * wb.w;
      }
    }
    *(float4*)(sbuf + ox * 96 + d0)     = *(float4*)acc;
    *(float4*)(sbuf + ox * 96 + d0 + 4) = *(float4*)(acc + 4);
  }
  __syncthreads();

  // LN: 8 lanes per row, 12 channels per lane, 28 rows in one pass
  const int grp = tid >> 3, l8 = tid & 7;
  if (grp < 28){
    const int ox = grp, d0 = l8 * 12;
    float x[12];
    *(float4*)x       = *(const float4*)(sbuf + ox * 96 + d0);
    *(float4*)(x + 4) = *(const float4*)(sbuf + ox * 96 + d0 + 4);
    *(float4*)(x + 8) = *(const float4*)(sbuf + ox * 96 + d0 + 8);
    float s = 0.f, ss = 0.f;
#pragma unroll
    for (int j = 0; j < 12; ++j){ s += x[j]; ss += x[j] * x[j]; }
#pragma unroll
    for (int d = 1; d < 8; d <<= 1){ s += __shfl_xor(s, d); ss += __shfl_xor(ss, d); }
    const float mean = s * (1.f / 96.f);
    const float var  = ss * (1.f / 96.f) - mean * mean;
    const float rstd = rsqrtf(var + 1e-6f);
    const int n = oy * 28 + ox;
    const size_t bh = (size_t)(b * 4 + h);
    float y[12];
#pragma unroll
    for (int j = 0; j < 12; ++j)
      y[j] = (x[j] - mean) * rstd * sg[d0 + j] + sb[d0 + j];
    if (which == 0){
      const size_t idx = (bh * 784 + n) * 96 + d0;
#pragma unroll
      for (int c = 0; c < 3; ++c){
        short4v p;
        p[0] = (short)f2bf(y[c*4]);   p[1] = (short)f2bf(y[c*4+1]);
        p[2] = (short)f2bf(y[c*4+2]); p[3] = (short)f2bf(y[c*4+3]);
        *(short4v*)(qp + idx + c * 4) = p;
        *(float4*)(qpf + idx + c * 4) = *(const float4*)(y + c * 4);
      }
    } else if (which == 1){
      const size_t idx = (bh * 784 + n) * 160;
#pragma unroll
      for (int c = 0; c < 3; ++c){
        short4v p;
        p[0] = (short)f2bf(y[c*4]   * KSCALE); p[1] = (short)f2bf(y[c*4+1] * KSCALE);
        p[2] = (short)f2bf(y[c*4+2] * KSCALE); p[3] = (short)f2bf(y[c*4+3] * KSCALE);
        *(short4v*)(kp + idx + d0 + c * 4) = p;
      }
      // one-hot extension granule (8 shorts at col 96 + l8*8)
      short8 oh;
#pragma unroll
      for (int jj = 0; jj < 8; ++jj){
        const int pcol = 96 + l8 * 8 + jj;
        unsigned short v = 0;
        if (pcol == 96 + oy)  v = 0x3F80;   // 1.0 bf16
        if (pcol == 128 + ox) v = 0x3F80;
        oh[jj] = (short)v;
      }
      *(short8*)(kp + idx + 96 + l8 * 8) = oh;
    } else {
#pragma unroll
      for (int j = 0; j < 12; ++j)
        vpt[(bh * 96 + d0 + j) * 784 + n] = f2bf(y[j]);
    }
  }
}

// ---------------- K4: fused attention, one-hot rel-pos in the MFMA ------------
// 448 blocks x 512 thr, 128 q-rows, 13 K-tiles (round-5 structure).
// sKm 256B rows (XOR r&7) + sKe 64B rows; P overlays sKm[cur]; G overlays sKm[1].
__global__ __launch_bounds__(512, 4) void k_attn(
    const unsigned short* __restrict__ qp, const unsigned short* __restrict__ kp,
    const unsigned short* __restrict__ vpt, const float* __restrict__ qpf,
    const unsigned short* __restrict__ rhb, const unsigned short* __restrict__ rwb,
    float* __restrict__ out){
  __shared__ unsigned short sKm[2][64 * 128];  // 2 x 16KB main (K cols 0..127)
  __shared__ unsigned short sKe[2][64 * 32];   // 2 x 4KB  ext  (K cols 128..159)
  __shared__ unsigned short sV[96 * 64];       // 12KB V^T tile [d][k]

  // XCD mapping: all 7 q-blocks of one bh land on one XCD (K/V L2-resident)
  const int s = blockIdx.x, xcd = s & 7, slot = s >> 3;
  const int bh = xcd * 8 + slot / 7, qb = slot - (slot / 7) * 7;
  const int b = bh >> 2, h = bh & 3;
  const int tid = threadIdx.x, w = tid >> 6, l = tid & 63;
  const int l15 = l & 15, l4 = l >> 4;
  const size_t baseq = (size_t)bh * 784 * 96;
  const size_t basek = (size_t)bh * 784 * 160;
  const f32x4 z4 = {0.f, 0.f, 0.f, 0.f};
  const int qrl = w * 16 + l15;                 // local q row 0..127
  int q_l = qb * 128 + qrl; if (q_l > 783) q_l = 783;

  auto stageK = [&](int t, int buf){
    int krr = t * 64;
#pragma unroll
    for (int rd = 0; rd < 2; ++rd){
      const int off = rd * 8192 + (tid << 4);
      const int row = off >> 8;                  // 256B rows
      const int gr  = (off >> 4) & 15;
      const int sg_ = (gr & 8) | ((gr ^ row) & 7);
      int kr = krr + row; if (kr > 783) kr = 783;
      gload16((const char*)kp + ((size_t)kr * 160 + basek + sg_ * 8) * 2,
              (char*)sKm[buf] + off);
    }
    if (tid < 256){
      const int off = tid << 4;
      const int row = off >> 6;                  // 64B rows
      const int gr  = (off >> 4) & 3;
      const int sg_ = (gr ^ (row >> 1)) & 3;
      int kr = krr + row; if (kr > 783) kr = 783;
      gload16((const char*)kp + ((size_t)kr * 160 + basek + 128 + sg_ * 8) * 2,
              (char*)sKe[buf] + off);
    }
  };
  short8 vreg[2];
  auto loadV = [&](int t){
    if (tid < 384){
#pragma unroll
      for (int i = 0; i < 2; ++i){
        const int off = (tid * 2 + i) << 4;      // bytes in sV
        const int r = off >> 7;                  // d row (128B rows)
        const int g = ((off >> 4) & 7) ^ (r & 7);
        int koff = t * 64 + g * 8; if (koff + 8 > 784) koff = 0;  // masked by P=0
        vreg[i] = *(const short8*)(vpt + (size_t)(bh * 96 + r) * 784 + koff);
      }
    }
  };
  auto writeV = [&](){
    if (tid < 384){
#pragma unroll
      for (int i = 0; i < 2; ++i)
        *(short8*)((char*)sV + ((tid * 2 + i) << 4)) = vreg[i];
    }
  };

  stageK(0, 0);
  loadV(0);

  // ---- Q' fragments: qf[0..2] = Q (bf16), qf[3] = Gh, qf[4] = Gw ----
  short8 qf[5];
#pragma unroll
  for (int ks = 0; ks < 3; ++ks)
    qf[ks] = *(const short8*)(qp + baseq + (size_t)q_l * 96 + ks * 32 + l4 * 8);

  const int hh = (q_l * 2341) >> 16;             // /28 (exact for <=847)
  const int ww = q_l - hh * 28;
  const int h0 = (qb * 128) / 28;

  // G tables via MFMA from pre-scaled bf16 rel tables; overlay on sKm[1]
  {
    unsigned short* sGh = sKm[1];
    unsigned short* sGw = sKm[1] + 4096;
    f32x4 gh[3] = {z4, z4, z4}, gw[4] = {z4, z4, z4, z4};
#pragma unroll
    for (int nf = 0; nf < 3; ++nf){
      int j = h0 + nf * 16 + l15; if (j > 54) j = 54;
#pragma unroll
      for (int ks = 0; ks < 3; ++ks)
        gh[nf] = mfma16(*(const short8*)(rhb + j * 96 + ks * 32 + l4 * 8), qf[ks], gh[nf]);
    }
#pragma unroll
    for (int nf = 0; nf < 4; ++nf){
      int j = nf * 16 + l15; if (j > 54) j = 54;
#pragma unroll
      for (int ks = 0; ks < 3; ++ks)
        gw[nf] = mfma16(*(const short8*)(rwb + j * 96 + ks * 32 + l4 * 8), qf[ks], gw[nf]);
    }
    if (l4 == 0){
      *(short4v*)(sGh + qrl * 32 + 28) = (short4v)0;
      *(short4v*)(sGw + qrl * 32 + 28) = (short4v)0;
    }
#pragma unroll
    for (int nf = 0; nf < 3; ++nf)
#pragma unroll
      for (int reg = 0; reg < 4; ++reg){
        const int j = h0 + nf * 16 + l4 * 4 + reg;
        const int kh = hh + 27 - j;
        if ((unsigned)kh < 28u) sGh[qrl * 32 + kh] = f2bf(gh[nf][reg]);
      }
#pragma unroll
    for (int nf = 0; nf < 4; ++nf)
#pragma unroll
      for (int reg = 0; reg < 4; ++reg){
        const int j = nf * 16 + l4 * 4 + reg;
        const int kw = ww + 27 - j;
        if ((unsigned)kw < 28u) sGw[qrl * 32 + kw] = f2bf(gw[nf][reg]);
      }
    qf[3] = *(const short8*)(sGh + qrl * 32 + l4 * 8);
    qf[4] = *(const short8*)(sGw + qrl * 32 + l4 * 8);
  }

  float m = -1e30f, lsum = 0.f;
  f32x4 acc[6];
#pragma unroll
  for (int i = 0; i < 6; ++i) acc[i] = z4;

  writeV();
  __syncthreads();   // drains K'(0) staging; sV visible; sG reads done

  for (int kt = 0; kt < 13; ++kt){
    const int cur = kt & 1;
    if (kt < 12){ loadV(kt + 1); stageK(kt + 1, cur ^ 1); }

    // ---- S'^T = mfma(K', Q'): finished log2-logits, lane holds k-rows ----
    f32x4 sfr[4] = {z4, z4, z4, z4};
#pragma unroll
    for (int ks = 0; ks < 4; ++ks){
      const int g = ks * 4 + l4;
#pragma unroll
      for (int nf = 0; nf < 4; ++nf){
        const int r = nf * 16 + l15;
        const int sl = (g & 8) | ((g ^ r) & 7);
        const short8 kb = *(const short8*)(sKm[cur] + r * 128 + sl * 8);
        sfr[nf] = mfma16(kb, qf[ks], sfr[nf]);
      }
    }
#pragma unroll
    for (int nf = 0; nf < 4; ++nf){
      const int r = nf * 16 + l15;
      const int sl = (l4 ^ (r >> 1)) & 3;
      const short8 kb = *(const short8*)(sKe[cur] + r * 32 + sl * 8);
      sfr[nf] = mfma16(kb, qf[4], sfr[nf]);
    }
    if (kt == 12){                 // keys 784..831 invalid: frags nf>=1
      const f32x4 m30 = {-1e30f, -1e30f, -1e30f, -1e30f};
      sfr[1] = m30; sfr[2] = m30; sfr[3] = m30;
    }

    // ---- lane-local online softmax (log2 domain) ----
    float mx;
    {
      float a0 = fmaxf(fmaxf(sfr[0][0], sfr[0][1]), fmaxf(sfr[0][2], sfr[0][3]));
      float a1 = fmaxf(fmaxf(sfr[1][0], sfr[1][1]), fmaxf(sfr[1][2], sfr[1][3]));
      float a2 = fmaxf(fmaxf(sfr[2][0], sfr[2][1]), fmaxf(sfr[2][2], sfr[2][3]));
      float a3 = fmaxf(fmaxf(sfr[3][0], sfr[3][1]), fmaxf(sfr[3][2], sfr[3][3]));
      mx = fmaxf(fmaxf(a0, a1), fmaxf(a2, a3));
    }
    mx = fmaxf(mx, __shfl_xor(mx, 16));
    mx = fmaxf(mx, __shfl_xor(mx, 32));
    const float mn = fmaxf(m, mx);
    const float al = exp2f(m - mn);
    m = mn;
    float sum;
    {
#pragma unroll
      for (int nf = 0; nf < 4; ++nf)
#pragma unroll
        for (int reg = 0; reg < 4; ++reg)
          sfr[nf][reg] = exp2f(sfr[nf][reg] - mn);
      float s0 = (sfr[0][0] + sfr[0][1]) + (sfr[0][2] + sfr[0][3]);
      float s1 = (sfr[1][0] + sfr[1][1]) + (sfr[1][2] + sfr[1][3]);
      float s2 = (sfr[2][0] + sfr[2][1]) + (sfr[2][2] + sfr[2][3]);
      float s3 = (sfr[3][0] + sfr[3][1]) + (sfr[3][2] + sfr[3][3]);
      sum = (s0 + s1) + (s2 + s3);
    }
    sum += __shfl_xor(sum, 16);
    sum += __shfl_xor(sum, 32);
    lsum = lsum * al + sum;

    __syncthreads();   // B1: all QK' reads of sKm/sKe[cur] done -> free for P

    // ---- P -> sKm[cur] (128 rows x 128B, per-wave-private rows) ----
    unsigned short* sPp = sKm[cur];
#pragma unroll
    for (int nf = 0; nf < 4; ++nf){
      short4v p4;
      p4[0] = (short)f2bf(sfr[nf][0]); p4[1] = (short)f2bf(sfr[nf][1]);
      p4[2] = (short)f2bf(sfr[nf][2]); p4[3] = (short)f2bf(sfr[nf][3]);
      char* dst = (char*)sPp + qrl * 128 + (((nf * 2 + (l4 >> 1)) ^ (l15 & 7)) << 4) + ((l4 & 1) << 3);
      *(short4v*)dst = p4;
    }
    // rescale O^T by per-lane alpha
#pragma unroll
    for (int i = 0; i < 6; ++i)
#pragma unroll
      for (int reg = 0; reg < 4; ++reg)
        acc[i][reg] *= al;

    // ---- O^T += mfma(V^T, P) ----
#pragma unroll
    for (int ks = 0; ks < 2; ++ks){
      const short8 pb = *(const short8*)((char*)sPp + qrl * 128 + (((ks * 4 + l4) ^ (l15 & 7)) << 4));
#pragma unroll
      for (int nf = 0; nf < 6; ++nf){
        const int r = nf * 16 + l15;
        const int sl = (ks * 4 + l4) ^ (r & 7);
        const short8 vb = *(const short8*)(sV + r * 64 + sl * 8);
        acc[nf] = mfma16(vb, pb, acc[nf]);
      }
    }

    if (kt < 12){
      __syncthreads();   // B2: PV reads of sV + P done; staging drained
      writeV();
      __syncthreads();   // B3: sV(t+1) visible
    }
  }

  // ---- epilogue: O[q][d] = O^T/lsum + residual ----
  const int qg = qb * 128 + qrl;
  if (qg < 784){
    const float rcp = 1.f / lsum;
    const float* qrow = qpf + baseq + (size_t)qg * 96;
    float* orow = out + ((size_t)b * 784 + qg) * 384 + h * 96;
#pragma unroll
    for (int nf = 0; nf < 6; ++nf)
#pragma unroll
      for (int reg = 0; reg < 4; ++reg){
        const int d = nf * 16 + l4 * 4 + reg;
        orow[d] = acc[nf][reg] * rcp + qrow[d];
      }
  }
}

// ---------------- launcher -----------------------------------------------------
extern "C" void kernel_launch(void* const* d_in, const int* in_sizes, int n_in,
                              void* d_out, int out_size, void* d_ws, size_t ws_size,
                              hipStream_t stream){
  const float* hs  = (const float*)d_in[0];
  const float* qw  = (const float*)d_in[1];
  const float* qb  = (const float*)d_in[2];
  const float* pwq = (const float*)d_in[3];
  const float* pwk = (const float*)d_in[4];
  const float* pwv = (const float*)d_in[5];
  const float* gq  = (const float*)d_in[6];
  const float* bq  = (const float*)d_in[7];
  const float* gk  = (const float*)d_in[8];
  const float* bk  = (const float*)d_in[9];
  const float* gv  = (const float*)d_in[10];
  const float* bv  = (const float*)d_in[11];
  const float* rh  = (const float*)d_in[12];
  const float* rw  = (const float*)d_in[13];
  float* out = (float*)d_out;

  char* ws = (char*)d_ws;
  size_t off = 0;
  auto take = [&](size_t n)->char*{ char* p = ws + off; off += (n + 255) & ~(size_t)255; return p; };
  unsigned short* hsb = (unsigned short*)take((size_t)50176 * 192 * 2);
  unsigned short* wtb = (unsigned short*)take((size_t)1152 * 192 * 2);
  unsigned short* qkv = (unsigned short*)take((size_t)50176 * 1152 * 2);
  unsigned short* qpb = (unsigned short*)take((size_t)64 * 784 * 96 * 2);
  unsigned short* kpb = (unsigned short*)take((size_t)64 * 784 * 160 * 2);   // extended K'
  unsigned short* vpt = (unsigned short*)take((size_t)64 * 784 * 96 * 2);
  float* qpf          = (float*)take((size_t)64 * 784 * 96 * 4);
  unsigned short* rhb = (unsigned short*)take((size_t)55 * 96 * 2);
  unsigned short* rwb = (unsigned short*)take((size_t)55 * 96 * 2);

  hipLaunchKernelGGL(k_convert, dim3(1024), dim3(256), 0, stream,
                     (const float4*)hs, qw, rh, rw, hsb, wtb, rhb, rwb);
  hipLaunchKernelGGL(k_gemm, dim3(392 * 9), dim3(256), 0, stream, hsb, wtb, qb, qkv);
  hipLaunchKernelGGL(k_pool_ln, dim3(5376), dim3(384), 0, stream, qkv,
                     pwq, pwk, pwv, gq, bq, gk, bk, gv, bv, qpb, kpb, vpt, qpf);
  hipLaunchKernelGGL(k_attn, dim3(448), dim3(512), 0, stream,
                     qpb, kpb, vpt, qpf, rhb, rwb, out);
}

// Round 9
// 244.952 us; speedup vs baseline: 1.2084x; 1.0597x over previous
//
#include <hip/hip_runtime.h>

#define DEVI __device__ __forceinline__

typedef __attribute__((ext_vector_type(8))) short short8;
typedef __attribute__((ext_vector_type(4))) short short4v;
typedef __attribute__((ext_vector_type(4))) float f32x4;
typedef __attribute__((ext_vector_type(4))) unsigned int u32x4;

#define ATTN_SCALE 0.10206207261596575f  // 96^-0.5
#define LOG2E      1.4426950408889634f
#define KSCALE     (ATTN_SCALE * LOG2E)

DEVI unsigned short f2bf(float f){
  unsigned u = __float_as_uint(f);
  u += 0x7fff + ((u >> 16) & 1);          // RNE
  return (unsigned short)(u >> 16);
}
DEVI float bf2f(unsigned short h){ return __uint_as_float(((unsigned)h) << 16); }

DEVI void gload16(const void* g, void* l){
  __builtin_amdgcn_global_load_lds((const __attribute__((address_space(1))) void*)g,
                                   (__attribute__((address_space(3))) void*)l, 16, 0, 0);
}

DEVI f32x4 mfma16(short8 a, short8 b, f32x4 c){
  return __builtin_amdgcn_mfma_f32_16x16x32_bf16(a, b, c, 0, 0, 0);
}

// ---------------- K1: f32->bf16 converts: hidden, qkv_w^T, rel tables ----------
__global__ __launch_bounds__(256) void k_convert(const float4* __restrict__ hs4,
    const float* __restrict__ w, const float* __restrict__ rh, const float* __restrict__ rw,
    unsigned short* __restrict__ hsb, unsigned short* __restrict__ wt,
    unsigned short* __restrict__ rhb, unsigned short* __restrict__ rwb){
  const int stride = gridDim.x * 256;
  const int t0 = blockIdx.x * 256 + threadIdx.x;
  const int n4 = (50176 * 192) / 4;
  for (int i = t0; i < n4; i += stride){
    float4 v = hs4[i];
    uint2 p;
    p.x = (unsigned)f2bf(v.x) | ((unsigned)f2bf(v.y) << 16);
    p.y = (unsigned)f2bf(v.z) | ((unsigned)f2bf(v.w) << 16);
    ((uint2*)hsb)[i] = p;
  }
  for (int i = t0; i < 192 * 1152; i += stride){
    int k = i / 1152, n = i - k * 1152;
    wt[n * 192 + k] = f2bf(w[i]);
  }
  for (int i = t0; i < 55 * 96; i += stride){
    rhb[i] = f2bf(rh[i] * LOG2E);
    rwb[i] = f2bf(rw[i] * LOG2E);
  }
}

// ---------------- K2: QKV GEMM  C[50176,1152] = A[50176,192] * W[192,1152] + b --
__global__ __launch_bounds__(256) void k_gemm(const unsigned short* __restrict__ A,
    const unsigned short* __restrict__ Bt,   // [1152][192] (pre-transposed, K-major)
    const float* __restrict__ bias, unsigned short* __restrict__ C){
  __shared__ unsigned short sA[2][128 * 64];
  __shared__ unsigned short sB[2][128 * 64];
  // bijective XCD swizzle: 3528 = 8 * 441
  const int bid = (blockIdx.x & 7) * 441 + (blockIdx.x >> 3);
  const int bn = bid % 9, bm = bid / 9;
  const int tid = threadIdx.x, w = tid >> 6, l = tid & 63;
  const int wr = (w >> 1) * 64, wc = (w & 1) * 64;
  const int l15 = l & 15, l4 = l >> 4;
  const f32x4 z4 = {0.f, 0.f, 0.f, 0.f};
  f32x4 acc[4][4];
#pragma unroll
  for (int i = 0; i < 4; ++i)
#pragma unroll
    for (int j = 0; j < 4; ++j) acc[i][j] = z4;

  auto stage = [&](int kk, int buf){
    const int k0 = kk * 64;
#pragma unroll
    for (int i = 0; i < 4; ++i){
      const int ib = (w * 4 + i) << 10;
      const int Lb = ib + (l << 4);
      const int r  = Lb >> 7;
      const int g  = ((Lb >> 4) & 7) ^ (r & 7);
      gload16((const char*)A  + (size_t)(bm * 128 + r) * 384 + k0 * 2 + g * 16, (char*)sA[buf] + ib);
      gload16((const char*)Bt + (size_t)(bn * 128 + r) * 384 + k0 * 2 + g * 16, (char*)sB[buf] + ib);
    }
  };

  stage(0, 0);
  __syncthreads();
  for (int kk = 0; kk < 3; ++kk){
    const int buf = kk & 1;
    if (kk < 2) stage(kk + 1, buf ^ 1);
#pragma unroll
    for (int ks = 0; ks < 2; ++ks){
      short8 av[4], bv[4];
#pragma unroll
      for (int mf = 0; mf < 4; ++mf){
        const int r = wr + mf * 16 + l15;
        const int slot = (ks * 4 + l4) ^ (r & 7);
        av[mf] = *(const short8*)(sA[buf] + r * 64 + slot * 8);
      }
#pragma unroll
      for (int nf = 0; nf < 4; ++nf){
        const int r = wc + nf * 16 + l15;
        const int slot = (ks * 4 + l4) ^ (r & 7);
        bv[nf] = *(const short8*)(sB[buf] + r * 64 + slot * 8);
      }
      // swapped operands: acc[mf][nf] holds C[row=wr+mf*16+l15][col=wc+nf*16+l4*4+reg]
#pragma unroll
      for (int mf = 0; mf < 4; ++mf)
#pragma unroll
        for (int nf = 0; nf < 4; ++nf)
          acc[mf][nf] = mfma16(bv[nf], av[mf], acc[mf][nf]);
    }
    if (kk < 2) __syncthreads();
  }

  // ---- epilogue: bias + bounce through LDS, coalesced short8 global stores ----
  __syncthreads();                            // all MFMA LDS reads done
  unsigned short* sC = (unsigned short*)sA;   // 32KB = 128 rows x 128 cols
#pragma unroll
  for (int nf = 0; nf < 4; ++nf){
    const int colq = wc + nf * 16 + l4 * 4;
    const float4 b4 = *(const float4*)(bias + bn * 128 + colq);
#pragma unroll
    for (int mf = 0; mf < 4; ++mf){
      const int row = wr + mf * 16 + l15;
      short4v p;
      p[0] = (short)f2bf(acc[mf][nf][0] + b4.x);
      p[1] = (short)f2bf(acc[mf][nf][1] + b4.y);
      p[2] = (short)f2bf(acc[mf][nf][2] + b4.z);
      p[3] = (short)f2bf(acc[mf][nf][3] + b4.w);
      const int slot = (colq >> 3) ^ (row & 7);
      *(short4v*)(sC + row * 128 + slot * 8 + (colq & 7)) = p;
    }
  }
  __syncthreads();
#pragma unroll
  for (int i = 0; i < 8; ++i){
    const int row = i * 16 + w * 4 + l4;
    const int slot = l15 ^ (row & 7);
    const short8 v = *(const short8*)(sC + row * 128 + slot * 8);
    *(short8*)(C + (size_t)(bm * 128 + row) * 1152 + bn * 128 + l15 * 8) = v;
  }
}

// ---------------- K3: depthwise 3x3 s2 pool + LayerNorm (vectorized) -----------
// kp is the EXTENDED K' [bh][784][160]: cols 0-95 = K*KSCALE (bf16),
// 96-123 = onehot(kh=n/28), 124-127 = 0, 128-155 = onehot(kw=n%28), 156-159 = 0.
__global__ __launch_bounds__(384) void k_pool_ln(const unsigned short* __restrict__ qkv,
    const float* __restrict__ wq, const float* __restrict__ wk, const float* __restrict__ wv,
    const float* __restrict__ gq, const float* __restrict__ bq,
    const float* __restrict__ gk, const float* __restrict__ bk,
    const float* __restrict__ gv, const float* __restrict__ bv,
    unsigned short* __restrict__ qp, unsigned short* __restrict__ kp,
    unsigned short* __restrict__ vpt){
  __shared__ float swt[9 * 96];          // weights transposed [tap][d]
  __shared__ float sg[96], sb[96];
  __shared__ float sbuf[28 * 96];
  const int bid = blockIdx.x;
  const int oy = bid % 28, h = (bid / 28) & 3, b = (bid / 112) & 15, which = bid / 1792;
  const float* wsel = which == 0 ? wq : (which == 1 ? wk : wv);
  const float* gsel = which == 0 ? gq : (which == 1 ? gk : gv);
  const float* bsel = which == 0 ? bq : (which == 1 ? bk : bv);
  const int tid = threadIdx.x;
  for (int i = tid; i < 864; i += 384){
    const int d = i / 9, t = i - d * 9;
    swt[t * 96 + d] = wsel[i];
  }
  if (tid < 96){ sg[tid] = gsel[tid]; sb[tid] = bsel[tid]; }
  __syncthreads();

  const int colbase = which * 384 + h * 96;
  if (tid < 336){
    const int ox = tid / 12, d0 = (tid - ox * 12) * 8;
    float acc[8] = {0.f,0.f,0.f,0.f,0.f,0.f,0.f,0.f};
#pragma unroll
    for (int ky = 0; ky < 3; ++ky){
      const int iy = oy * 2 + ky - 1;
      if ((unsigned)iy >= 56u) continue;
      const unsigned short* rowp = qkv + (size_t)(b * 3136 + iy * 56) * 1152 + colbase + d0;
#pragma unroll
      for (int kx = 0; kx < 3; ++kx){
        const int ix = ox * 2 + kx - 1;
        if ((unsigned)ix >= 56u) continue;
        const u32x4 raw = *(const u32x4*)(rowp + (size_t)ix * 1152);
        const float* wv8 = swt + (ky * 3 + kx) * 96 + d0;
        const float4 wa = *(const float4*)wv8;
        const float4 wb = *(const float4*)(wv8 + 4);
        acc[0] += __uint_as_float(raw[0] << 16)         * wa.x;
        acc[1] += __uint_as_float(raw[0] & 0xffff0000u) * wa.y;
        acc[2] += __uint_as_float(raw[1] << 16)         * wa.z;
        acc[3] += __uint_as_float(raw[1] & 0xffff0000u) * wa.w;
        acc[4] += __uint_as_float(raw[2] << 16)         * wb.x;
        acc[5] += __uint_as_float(raw[2] & 0xffff0000u) * wb.y;
        acc[6] += __uint_as_float(raw[3] << 16)         * wb.z;
        acc[7] += __uint_as_float(raw[3] & 0xffff0000u) * wb.w;
      }
    }
    *(float4*)(sbuf + ox * 96 + d0)     = *(float4*)acc;
    *(float4*)(sbuf + ox * 96 + d0 + 4) = *(float4*)(acc + 4);
  }
  __syncthreads();

  // LN: 8 lanes per row, 12 channels per lane, 28 rows in one pass
  const int grp = tid >> 3, l8 = tid & 7;
  if (grp < 28){
    const int ox = grp, d0 = l8 * 12;
    float x[12];
    *(float4*)x       = *(const float4*)(sbuf + ox * 96 + d0);
    *(float4*)(x + 4) = *(const float4*)(sbuf + ox * 96 + d0 + 4);
    *(float4*)(x + 8) = *(const float4*)(sbuf + ox * 96 + d0 + 8);
    float s = 0.f, ss = 0.f;
#pragma unroll
    for (int j = 0; j < 12; ++j){ s += x[j]; ss += x[j] * x[j]; }
#pragma unroll
    for (int d = 1; d < 8; d <<= 1){ s += __shfl_xor(s, d); ss += __shfl_xor(ss, d); }
    const float mean = s * (1.f / 96.f);
    const float var  = ss * (1.f / 96.f) - mean * mean;
    const float rstd = rsqrtf(var + 1e-6f);
    const int n = oy * 28 + ox;
    const size_t bh = (size_t)(b * 4 + h);
    float y[12];
#pragma unroll
    for (int j = 0; j < 12; ++j)
      y[j] = (x[j] - mean) * rstd * sg[d0 + j] + sb[d0 + j];
    if (which == 0){
      const size_t idx = (bh * 784 + n) * 96 + d0;
#pragma unroll
      for (int c = 0; c < 3; ++c){
        short4v p;
        p[0] = (short)f2bf(y[c*4]);   p[1] = (short)f2bf(y[c*4+1]);
        p[2] = (short)f2bf(y[c*4+2]); p[3] = (short)f2bf(y[c*4+3]);
        *(short4v*)(qp + idx + c * 4) = p;
      }
    } else if (which == 1){
      const size_t idx = (bh * 784 + n) * 160;
#pragma unroll
      for (int c = 0; c < 3; ++c){
        short4v p;
        p[0] = (short)f2bf(y[c*4]   * KSCALE); p[1] = (short)f2bf(y[c*4+1] * KSCALE);
        p[2] = (short)f2bf(y[c*4+2] * KSCALE); p[3] = (short)f2bf(y[c*4+3] * KSCALE);
        *(short4v*)(kp + idx + d0 + c * 4) = p;
      }
      // one-hot extension granule (8 shorts at col 96 + l8*8)
      short8 oh;
#pragma unroll
      for (int jj = 0; jj < 8; ++jj){
        const int pcol = 96 + l8 * 8 + jj;
        unsigned short v = 0;
        if (pcol == 96 + oy)  v = 0x3F80;   // 1.0 bf16
        if (pcol == 128 + ox) v = 0x3F80;
        oh[jj] = (short)v;
      }
      *(short8*)(kp + idx + 96 + l8 * 8) = oh;
    } else {
#pragma unroll
      for (int j = 0; j < 12; ++j)
        vpt[(bh * 96 + d0 + j) * 784 + n] = f2bf(y[j]);
    }
  }
}

// ---------------- K4: fused attention — 1 barrier per K-tile -------------------
// 448 blocks x 512 thr, 128 q-rows, 13 K-tiles. Dedicated sP (no B1);
// V double-buffered via global_load_lds (no writeV/B3). setprio around MFMA.
__global__ __launch_bounds__(512, 4) void k_attn(
    const unsigned short* __restrict__ qp, const unsigned short* __restrict__ kp,
    const unsigned short* __restrict__ vpt,
    const unsigned short* __restrict__ rhb, const unsigned short* __restrict__ rwb,
    float* __restrict__ out){
  __shared__ unsigned short sKm[2][64 * 128];  // 2 x 16KB main (K cols 0..127)
  __shared__ unsigned short sKe[2][64 * 32];   // 2 x 4KB  ext  (K cols 128..159)
  __shared__ unsigned short sV[2][96 * 64];    // 2 x 12KB V^T tile [d][k]
  __shared__ unsigned short sP[128 * 64];      // 16KB P [q][k], wave-private rows

  // XCD mapping: all 7 q-blocks of one bh land on one XCD (K/V L2-resident)
  const int s = blockIdx.x, xcd = s & 7, slot = s >> 3;
  const int bh = xcd * 8 + slot / 7, qb = slot - (slot / 7) * 7;
  const int b = bh >> 2, h = bh & 3;
  const int tid = threadIdx.x, w = tid >> 6, l = tid & 63;
  const int l15 = l & 15, l4 = l >> 4;
  const size_t baseq = (size_t)bh * 784 * 96;
  const size_t basek = (size_t)bh * 784 * 160;
  const f32x4 z4 = {0.f, 0.f, 0.f, 0.f};
  const int qrl = w * 16 + l15;                 // local q row 0..127
  int q_l = qb * 128 + qrl; if (q_l > 783) q_l = 783;

  auto stageK = [&](int t, int buf){
    int krr = t * 64;
#pragma unroll
    for (int rd = 0; rd < 2; ++rd){
      const int off = rd * 8192 + (tid << 4);
      const int row = off >> 8;                  // 256B rows
      const int gr  = (off >> 4) & 15;
      const int sg_ = (gr & 8) | ((gr ^ row) & 7);
      int kr = krr + row; if (kr > 783) kr = 783;
      gload16((const char*)kp + ((size_t)kr * 160 + basek + sg_ * 8) * 2,
              (char*)sKm[buf] + off);
    }
    if (tid < 256){
      const int off = tid << 4;
      const int row = off >> 6;                  // 64B rows
      const int gr  = (off >> 4) & 3;
      const int sg_ = (gr ^ (row >> 1)) & 3;
      int kr = krr + row; if (kr > 783) kr = 783;
      gload16((const char*)kp + ((size_t)kr * 160 + basek + 128 + sg_ * 8) * 2,
              (char*)sKe[buf] + off);
    }
  };
  auto stageV = [&](int t, int buf){
    if (w < 6){                                  // 6 waves x 2KB = 12KB
#pragma unroll
      for (int i = 0; i < 2; ++i){
        const int off = w * 2048 + i * 1024 + (l << 4);
        const int r = off >> 7;                  // d row (128B rows)
        const int g = ((off >> 4) & 7) ^ (r & 7);
        int koff = t * 64 + g * 8; if (koff + 8 > 784) koff = 0;  // masked by P=0
        gload16((const char*)vpt + ((size_t)(bh * 96 + r) * 784 + koff) * 2,
                (char*)sV[buf] + off);
      }
    }
  };

  stageK(0, 0);
  stageV(0, 0);

  // ---- Q' fragments: qf[0..2] = Q (bf16), qf[3] = Gh, qf[4] = Gw ----
  short8 qf[5];
#pragma unroll
  for (int ks = 0; ks < 3; ++ks)
    qf[ks] = *(const short8*)(qp + baseq + (size_t)q_l * 96 + ks * 32 + l4 * 8);

  const int hh = (q_l * 2341) >> 16;             // /28 (exact for <=847)
  const int ww = q_l - hh * 28;
  const int h0 = (qb * 128) / 28;

  // G tables via MFMA from pre-scaled bf16 rel tables; overlay on sKm[1]
  {
    unsigned short* sGh = sKm[1];
    unsigned short* sGw = sKm[1] + 4096;
    f32x4 gh[3] = {z4, z4, z4}, gw[4] = {z4, z4, z4, z4};
#pragma unroll
    for (int nf = 0; nf < 3; ++nf){
      int j = h0 + nf * 16 + l15; if (j > 54) j = 54;
#pragma unroll
      for (int ks = 0; ks < 3; ++ks)
        gh[nf] = mfma16(*(const short8*)(rhb + j * 96 + ks * 32 + l4 * 8), qf[ks], gh[nf]);
    }
#pragma unroll
    for (int nf = 0; nf < 4; ++nf){
      int j = nf * 16 + l15; if (j > 54) j = 54;
#pragma unroll
      for (int ks = 0; ks < 3; ++ks)
        gw[nf] = mfma16(*(const short8*)(rwb + j * 96 + ks * 32 + l4 * 8), qf[ks], gw[nf]);
    }
    if (l4 == 0){
      *(short4v*)(sGh + qrl * 32 + 28) = (short4v)0;
      *(short4v*)(sGw + qrl * 32 + 28) = (short4v)0;
    }
#pragma unroll
    for (int nf = 0; nf < 3; ++nf)
#pragma unroll
      for (int reg = 0; reg < 4; ++reg){
        const int j = h0 + nf * 16 + l4 * 4 + reg;
        const int kh = hh + 27 - j;
        if ((unsigned)kh < 28u) sGh[qrl * 32 + kh] = f2bf(gh[nf][reg]);
      }
#pragma unroll
    for (int nf = 0; nf < 4; ++nf)
#pragma unroll
      for (int reg = 0; reg < 4; ++reg){
        const int j = nf * 16 + l4 * 4 + reg;
        const int kw = ww + 27 - j;
        if ((unsigned)kw < 28u) sGw[qrl * 32 + kw] = f2bf(gw[nf][reg]);
      }
    qf[3] = *(const short8*)(sGh + qrl * 32 + l4 * 8);
    qf[4] = *(const short8*)(sGw + qrl * 32 + l4 * 8);
  }

  float m = -1e30f, lsum = 0.f;
  f32x4 acc[6];
#pragma unroll
  for (int i = 0; i < 6; ++i) acc[i] = z4;

  __syncthreads();   // drains K'(0)/V(0) staging; sG reads done (sKm[1] free)

  for (int kt = 0; kt < 13; ++kt){
    const int cur = kt & 1;
    if (kt < 12){ stageV(kt + 1, cur ^ 1); stageK(kt + 1, cur ^ 1); }

    // ---- S'^T = mfma(K', Q'): finished log2-logits, lane holds k-rows ----
    f32x4 sfr[4] = {z4, z4, z4, z4};
    __builtin_amdgcn_s_setprio(1);
#pragma unroll
    for (int ks = 0; ks < 4; ++ks){
      const int g = ks * 4 + l4;
#pragma unroll
      for (int nf = 0; nf < 4; ++nf){
        const int r = nf * 16 + l15;
        const int sl = (g & 8) | ((g ^ r) & 7);
        const short8 kb = *(const short8*)(sKm[cur] + r * 128 + sl * 8);
        sfr[nf] = mfma16(kb, qf[ks], sfr[nf]);
      }
    }
#pragma unroll
    for (int nf = 0; nf < 4; ++nf){
      const int r = nf * 16 + l15;
      const int sl = (l4 ^ (r >> 1)) & 3;
      const short8 kb = *(const short8*)(sKe[cur] + r * 32 + sl * 8);
      sfr[nf] = mfma16(kb, qf[4], sfr[nf]);
    }
    __builtin_amdgcn_s_setprio(0);
    if (kt == 12){                 // keys 784..831 invalid: frags nf>=1
      const f32x4 m30 = {-1e30f, -1e30f, -1e30f, -1e30f};
      sfr[1] = m30; sfr[2] = m30; sfr[3] = m30;
    }

    // ---- lane-local online softmax (log2 domain) ----
    float mx;
    {
      float a0 = fmaxf(fmaxf(sfr[0][0], sfr[0][1]), fmaxf(sfr[0][2], sfr[0][3]));
      float a1 = fmaxf(fmaxf(sfr[1][0], sfr[1][1]), fmaxf(sfr[1][2], sfr[1][3]));
      float a2 = fmaxf(fmaxf(sfr[2][0], sfr[2][1]), fmaxf(sfr[2][2], sfr[2][3]));
      float a3 = fmaxf(fmaxf(sfr[3][0], sfr[3][1]), fmaxf(sfr[3][2], sfr[3][3]));
      mx = fmaxf(fmaxf(a0, a1), fmaxf(a2, a3));
    }
    mx = fmaxf(mx, __shfl_xor(mx, 16));
    mx = fmaxf(mx, __shfl_xor(mx, 32));
    const float mn = fmaxf(m, mx);
    const float al = exp2f(m - mn);
    m = mn;
    float sum;
    {
#pragma unroll
      for (int nf = 0; nf < 4; ++nf)
#pragma unroll
        for (int reg = 0; reg < 4; ++reg)
          sfr[nf][reg] = exp2f(sfr[nf][reg] - mn);
      float s0 = (sfr[0][0] + sfr[0][1]) + (sfr[0][2] + sfr[0][3]);
      float s1 = (sfr[1][0] + sfr[1][1]) + (sfr[1][2] + sfr[1][3]);
      float s2 = (sfr[2][0] + sfr[2][1]) + (sfr[2][2] + sfr[2][3]);
      float s3 = (sfr[3][0] + sfr[3][1]) + (sfr[3][2] + sfr[3][3]);
      sum = (s0 + s1) + (s2 + s3);
    }
    sum += __shfl_xor(sum, 16);
    sum += __shfl_xor(sum, 32);
    lsum = lsum * al + sum;

    // ---- P -> sP (dedicated buffer, per-wave-private rows, no barrier) ----
#pragma unroll
    for (int nf = 0; nf < 4; ++nf){
      short4v p4;
      p4[0] = (short)f2bf(sfr[nf][0]); p4[1] = (short)f2bf(sfr[nf][1]);
      p4[2] = (short)f2bf(sfr[nf][2]); p4[3] = (short)f2bf(sfr[nf][3]);
      char* dst = (char*)sP + qrl * 128 + (((nf * 2 + (l4 >> 1)) ^ (l15 & 7)) << 4) + ((l4 & 1) << 3);
      *(short4v*)dst = p4;
    }
    // rescale O^T by per-lane alpha
#pragma unroll
    for (int i = 0; i < 6; ++i)
#pragma unroll
      for (int reg = 0; reg < 4; ++reg)
        acc[i][reg] *= al;

    // ---- O^T += mfma(V^T, P) ----
    __builtin_amdgcn_s_setprio(1);
#pragma unroll
    for (int ks = 0; ks < 2; ++ks){
      const short8 pb = *(const short8*)((char*)sP + qrl * 128 + (((ks * 4 + l4) ^ (l15 & 7)) << 4));
#pragma unroll
      for (int nf = 0; nf < 6; ++nf){
        const int r = nf * 16 + l15;
        const int sl = (ks * 4 + l4) ^ (r & 7);
        const short8 vb = *(const short8*)(sV[cur] + r * 64 + sl * 8);
        acc[nf] = mfma16(vb, pb, acc[nf]);
      }
    }
    __builtin_amdgcn_s_setprio(0);

    if (kt < 12) __syncthreads();   // single barrier: staging(t+1) drained,
                                    // all reads of [cur] complete before reuse
  }

  // ---- epilogue: O[q][d] = O^T/lsum + residual (bf16 q) ----
  const int qg = qb * 128 + qrl;
  if (qg < 784){
    const float rcp = 1.f / lsum;
    const unsigned short* qrow = qp + baseq + (size_t)qg * 96;
    float* orow = out + ((size_t)b * 784 + qg) * 384 + h * 96;
#pragma unroll
    for (int nf = 0; nf < 6; ++nf){
      const int d0 = nf * 16 + l4 * 4;
      const short4v q4 = *(const short4v*)(qrow + d0);
#pragma unroll
      for (int reg = 0; reg < 4; ++reg)
        orow[d0 + reg] = acc[nf][reg] * rcp + bf2f((unsigned short)q4[reg]);
    }
  }
}

// ---------------- launcher -----------------------------------------------------
extern "C" void kernel_launch(void* const* d_in, const int* in_sizes, int n_in,
                              void* d_out, int out_size, void* d_ws, size_t ws_size,
                              hipStream_t stream){
  const float* hs  = (const float*)d_in[0];
  const float* qw  = (const float*)d_in[1];
  const float* qb  = (const float*)d_in[2];
  const float* pwq = (const float*)d_in[3];
  const float* pwk = (const float*)d_in[4];
  const float* pwv = (const float*)d_in[5];
  const float* gq  = (const float*)d_in[6];
  const float* bq  = (const float*)d_in[7];
  const float* gk  = (const float*)d_in[8];
  const float* bk  = (const float*)d_in[9];
  const float* gv  = (const float*)d_in[10];
  const float* bv  = (const float*)d_in[11];
  const float* rh  = (const float*)d_in[12];
  const float* rw  = (const float*)d_in[13];
  float* out = (float*)d_out;

  char* ws = (char*)d_ws;
  size_t off = 0;
  auto take = [&](size_t n)->char*{ char* p = ws + off; off += (n + 255) & ~(size_t)255; return p; };
  unsigned short* hsb = (unsigned short*)take((size_t)50176 * 192 * 2);
  unsigned short* wtb = (unsigned short*)take((size_t)1152 * 192 * 2);
  unsigned short* qkv = (unsigned short*)take((size_t)50176 * 1152 * 2);
  unsigned short* qpb = (unsigned short*)take((size_t)64 * 784 * 96 * 2);
  unsigned short* kpb = (unsigned short*)take((size_t)64 * 784 * 160 * 2);   // extended K'
  unsigned short* vpt = (unsigned short*)take((size_t)64 * 784 * 96 * 2);
  unsigned short* rhb = (unsigned short*)take((size_t)55 * 96 * 2);
  unsigned short* rwb = (unsigned short*)take((size_t)55 * 96 * 2);

  hipLaunchKernelGGL(k_convert, dim3(1024), dim3(256), 0, stream,
                     (const float4*)hs, qw, rh, rw, hsb, wtb, rhb, rwb);
  hipLaunchKernelGGL(k_gemm, dim3(392 * 9), dim3(256), 0, stream, hsb, wtb, qb, qkv);
  hipLaunchKernelGGL(k_pool_ln, dim3(5376), dim3(384), 0, stream, qkv,
                     pwq, pwk, pwv, gq, bq, gk, bk, gv, bv, qpb, kpb, vpt);
  hipLaunchKernelGGL(k_attn, dim3(448), dim3(512), 0, stream,
                     qpb, kpb, vpt, rhb, rwb, out);
}